// Round 2
// baseline (666.818 us; speedup 1.0000x reference)
//
#include <hip/hip_runtime.h>

typedef __bf16 bf16x8 __attribute__((ext_vector_type(8)));
typedef float f32x4 __attribute__((ext_vector_type(4)));

static __device__ __forceinline__ f32x4 mfma16(bf16x8 a, bf16x8 b, f32x4 c) {
    return __builtin_amdgcn_mfma_f32_16x16x32_bf16(a, b, c, 0, 0, 0);
}

// ---------------- prep kernel: weight transpose/convert + bias matrix ----------------
// ws layout:
//   wqkvT : 576*192 bf16  (221184 B)   wqkvT[n][k] = w_qkv[k][n]
//   wprojT: 192*192 bf16  ( 73728 B)   wprojT[n][k] = w_proj[k][n]
//   biasM : 6*64*64 f32   ( 98304 B)   biasM[h][i][j] (0 outside 49x49)
#define OFF_WPROJT (576 * 192 * 2)
#define OFF_BIASM (576 * 192 * 2 + 192 * 192 * 2)

__global__ __launch_bounds__(256) void wsa_prep(
    const float* __restrict__ w_qkv, const float* __restrict__ w_proj,
    const float* __restrict__ bias_table,
    __bf16* __restrict__ wqkvT, __bf16* __restrict__ wprojT,
    float* __restrict__ biasM)
{
    int tid = blockIdx.x * 256 + threadIdx.x;
    const int N1 = 576 * 192;
    const int N2 = 192 * 192;
    if (tid < N1) {
        int n = tid / 192, k = tid - n * 192;
        wqkvT[tid] = (__bf16)w_qkv[k * 576 + n];
    } else if (tid < N1 + N2) {
        int i = tid - N1;
        int n = i / 192, k = i - n * 192;
        wprojT[i] = (__bf16)w_proj[k * 192 + n];
    } else if (tid < N1 + N2 + 6 * 64 * 64) {
        int i = tid - N1 - N2;
        int h = i >> 12, ij = i & 4095, r = ij >> 6, c = ij & 63;
        float v = 0.0f;
        if (r < 49 && c < 49) {
            int rpi = (r / 7 - c / 7 + 6) * 13 + (r % 7 - c % 7 + 6);
            v = bias_table[rpi * 6 + h];
        }
        biasM[i] = v;
    }
}

// ---------------- fused main kernel: 1 window per 256-thread block ----------------
__global__ __launch_bounds__(256, 1) void wsa_main(
    const float* __restrict__ x, const float* __restrict__ bqkv,
    const __bf16* __restrict__ wqkvT, const __bf16* __restrict__ wprojT,
    const float* __restrict__ biasM, float* __restrict__ out)
{
    // pads: row strides 400B / 144B -> stride mod 32 banks == 4 words -> 2-way (free), 16B aligned
    __shared__ __bf16 q_s[64][200];
    __shared__ __bf16 k_s[64][200];
    __shared__ __bf16 vt_s[192][72];   // vt[dim][token]
    __shared__ __bf16 ao_s[64][200];   // attention out, [token][h*32+d]
    __shared__ __bf16 p_s[4][16][72];  // per-wave P tile (16 rows x 64 cols)

    const int win = blockIdx.x;
    const int tid = (int)threadIdx.x;
    const int wave = tid >> 6;
    const int lane = tid & 63;
    const int g = lane >> 4;  // 0..3
    const int c = lane & 15;  // 0..15
    const float scale = 0.17677669529663687f;  // 32^-0.5

    // ---- Phase 1: qkv = x @ Wqkv + b  (M=64 padded, K=192, N=576) ----
    bf16x8 xa[4][6];
    {
        const long xbase = (long)win * 49 * 192;
#pragma unroll
        for (int mt = 0; mt < 4; ++mt) {
            int row = mt * 16 + c;
            bool ok = row < 49;
#pragma unroll
            for (int kk = 0; kk < 6; ++kk) {
                bf16x8 a;
                if (ok) {
                    const float* p = x + xbase + (long)row * 192 + kk * 32 + g * 8;
                    f32x4 v0 = *(const f32x4*)p;
                    f32x4 v1 = *(const f32x4*)(p + 4);
#pragma unroll
                    for (int j = 0; j < 4; ++j) { a[j] = (__bf16)v0[j]; a[4 + j] = (__bf16)v1[j]; }
                } else {
#pragma unroll
                    for (int j = 0; j < 8; ++j) a[j] = (__bf16)0.0f;
                }
                xa[mt][kk] = a;
            }
        }
    }

    for (int t = 0; t < 9; ++t) {
        int nt = wave * 9 + t;
        int col = nt * 16 + c;  // 0..575
        float bv = bqkv[col];
        f32x4 acc[4];
#pragma unroll
        for (int mt = 0; mt < 4; ++mt) { f32x4 z = {0.f, 0.f, 0.f, 0.f}; acc[mt] = z; }
#pragma unroll
        for (int kk = 0; kk < 6; ++kk) {
            bf16x8 b = *(const bf16x8*)(wqkvT + (long)col * 192 + kk * 32 + g * 8);
#pragma unroll
            for (int mt = 0; mt < 4; ++mt) acc[mt] = mfma16(xa[mt][kk], b, acc[mt]);
        }
#pragma unroll
        for (int mt = 0; mt < 4; ++mt) {
#pragma unroll
            for (int r = 0; r < 4; ++r) {
                int row = mt * 16 + g * 4 + r;
                float v = acc[mt][r] + bv;
                if (col < 192)       q_s[row][col] = (__bf16)(v * scale);
                else if (col < 384)  k_s[row][col - 192] = (__bf16)v;
                else                 vt_s[col - 384][row] = (__bf16)v;
            }
        }
    }
    __syncthreads();

    // ---- Phase 2: per-head attention; wave owns m-tile = wave (16 query rows) ----
    const int mt = wave;
    for (int h = 0; h < 6; ++h) {
        bf16x8 aq = *(const bf16x8*)&q_s[mt * 16 + c][h * 32 + g * 8];
        f32x4 s4[4];
#pragma unroll
        for (int nt = 0; nt < 4; ++nt) {
            bf16x8 bk = *(const bf16x8*)&k_s[nt * 16 + c][h * 32 + g * 8];
            f32x4 z = {0.f, 0.f, 0.f, 0.f};
            s4[nt] = mfma16(aq, bk, z);
        }
        // bias + mask
        float sv[4][4];
        const float* bh = biasM + h * 4096;
#pragma unroll
        for (int nt = 0; nt < 4; ++nt) {
            int j = nt * 16 + c;
#pragma unroll
            for (int r = 0; r < 4; ++r) {
                int i = mt * 16 + g * 4 + r;
                float s = s4[nt][r] + bh[i * 64 + j];
                if (j >= 49) s = -1e30f;
                sv[nt][r] = s;
            }
        }
        // wave-parallel softmax over each row (16 lanes x 4 nt = 64 cols)
        float pinv[4];
#pragma unroll
        for (int r = 0; r < 4; ++r) {
            float m = fmaxf(fmaxf(sv[0][r], sv[1][r]), fmaxf(sv[2][r], sv[3][r]));
#pragma unroll
            for (int off = 1; off < 16; off <<= 1) m = fmaxf(m, __shfl_xor(m, off));
            float sum = 0.f;
#pragma unroll
            for (int nt = 0; nt < 4; ++nt) {
                float e = __expf(sv[nt][r] - m);
                sv[nt][r] = e;
                sum += e;
            }
#pragma unroll
            for (int off = 1; off < 16; off <<= 1) sum += __shfl_xor(sum, off);
            pinv[r] = 1.0f / sum;
        }
#pragma unroll
        for (int nt = 0; nt < 4; ++nt)
#pragma unroll
            for (int r = 0; r < 4; ++r)
                p_s[wave][g * 4 + r][nt * 16 + c] = (__bf16)(sv[nt][r] * pinv[r]);

        // PV: (16x64) @ (64x32)
        f32x4 o0, o1;
        { f32x4 z = {0.f, 0.f, 0.f, 0.f}; o0 = z; o1 = z; }
#pragma unroll
        for (int ks = 0; ks < 2; ++ks) {
            bf16x8 pa = *(const bf16x8*)&p_s[wave][c][ks * 32 + g * 8];
            bf16x8 bv0 = *(const bf16x8*)&vt_s[h * 32 + c][ks * 32 + g * 8];
            bf16x8 bv1 = *(const bf16x8*)&vt_s[h * 32 + 16 + c][ks * 32 + g * 8];
            o0 = mfma16(pa, bv0, o0);
            o1 = mfma16(pa, bv1, o1);
        }
#pragma unroll
        for (int r = 0; r < 4; ++r) {
            int row = mt * 16 + g * 4 + r;
            ao_s[row][h * 32 + c] = (__bf16)o0[r];
            ao_s[row][h * 32 + 16 + c] = (__bf16)o1[r];
        }
    }
    __syncthreads();

    // ---- Phase 3: out = ao @ Wproj  (M=64, K=192, N=192) ----
    bf16x8 pa2[4][6];
#pragma unroll
    for (int m2 = 0; m2 < 4; ++m2)
#pragma unroll
        for (int kk = 0; kk < 6; ++kk)
            pa2[m2][kk] = *(const bf16x8*)&ao_s[m2 * 16 + c][kk * 32 + g * 8];

    for (int t = 0; t < 3; ++t) {
        int nt = wave * 3 + t;
        int col = nt * 16 + c;  // 0..191
        f32x4 acc[4];
#pragma unroll
        for (int m2 = 0; m2 < 4; ++m2) { f32x4 z = {0.f, 0.f, 0.f, 0.f}; acc[m2] = z; }
#pragma unroll
        for (int kk = 0; kk < 6; ++kk) {
            bf16x8 b = *(const bf16x8*)(wprojT + (long)col * 192 + kk * 32 + g * 8);
#pragma unroll
            for (int m2 = 0; m2 < 4; ++m2) acc[m2] = mfma16(pa2[m2][kk], b, acc[m2]);
        }
#pragma unroll
        for (int m2 = 0; m2 < 4; ++m2) {
#pragma unroll
            for (int r = 0; r < 4; ++r) {
                int row = m2 * 16 + g * 4 + r;
                if (row < 49)
                    out[((long)win * 49 + row) * 192 + col] = acc[m2][r];
            }
        }
    }
}

extern "C" void kernel_launch(void* const* d_in, const int* in_sizes, int n_in,
                              void* d_out, int out_size, void* d_ws, size_t ws_size,
                              hipStream_t stream)
{
    const float* x = (const float*)d_in[0];
    const float* w_qkv = (const float*)d_in[1];
    const float* b_qkv = (const float*)d_in[2];
    const float* bias_table = (const float*)d_in[3];
    const float* w_proj = (const float*)d_in[4];
    float* out = (float*)d_out;

    char* ws = (char*)d_ws;
    __bf16* wqkvT = (__bf16*)ws;
    __bf16* wprojT = (__bf16*)(ws + OFF_WPROJT);
    float* biasM = (float*)(ws + OFF_BIASM);

    // prep: 576*192 + 192*192 + 6*64*64 = 172032 elements = 672 * 256
    wsa_prep<<<672, 256, 0, stream>>>(w_qkv, w_proj, bias_table, wqkvT, wprojT, biasM);
    wsa_main<<<4096, 256, 0, stream>>>(x, b_qkv, wqkvT, wprojT, biasM, out);
}

// Round 3
// 503.469 us; speedup vs baseline: 1.3244x; 1.3244x over previous
//
#include <hip/hip_runtime.h>

typedef __bf16 bf16x8 __attribute__((ext_vector_type(8)));
typedef float f32x4 __attribute__((ext_vector_type(4)));
typedef unsigned int u32;
typedef u32 u32x4 __attribute__((ext_vector_type(4)));

static __device__ __forceinline__ f32x4 mfma16(bf16x8 a, bf16x8 b, f32x4 c) {
    return __builtin_amdgcn_mfma_f32_16x16x32_bf16(a, b, c, 0, 0, 0);
}

static __device__ __forceinline__ u32 packbf(float a, float b) {
    unsigned short lo = __builtin_bit_cast(unsigned short, (__bf16)a);
    unsigned short hi = __builtin_bit_cast(unsigned short, (__bf16)b);
    return (u32)lo | ((u32)hi << 16);
}

// ---------------- prep kernel: weight transpose/convert + bias matrix ----------------
// ws layout:
//   wqkvT : 576*192 bf16  (221184 B)   wqkvT[n][k] = w_qkv[k][n]
//   wprojT: 192*192 bf16  ( 73728 B)   wprojT[n][k] = w_proj[k][n]
//   biasM : 6*64*64 f32   ( 98304 B)   biasM[h][i][j] (0 outside 49x49)
#define OFF_WPROJT (576 * 192 * 2)
#define OFF_BIASM (576 * 192 * 2 + 192 * 192 * 2)

__global__ __launch_bounds__(256) void wsa_prep(
    const float* __restrict__ w_qkv, const float* __restrict__ w_proj,
    const float* __restrict__ bias_table,
    __bf16* __restrict__ wqkvT, __bf16* __restrict__ wprojT,
    float* __restrict__ biasM)
{
    int tid = blockIdx.x * 256 + threadIdx.x;
    const int N1 = 576 * 192;
    const int N2 = 192 * 192;
    if (tid < N1) {
        int n = tid / 192, k = tid - n * 192;
        wqkvT[tid] = (__bf16)w_qkv[k * 576 + n];
    } else if (tid < N1 + N2) {
        int i = tid - N1;
        int n = i / 192, k = i - n * 192;
        wprojT[i] = (__bf16)w_proj[k * 192 + n];
    } else if (tid < N1 + N2 + 6 * 64 * 64) {
        int i = tid - N1 - N2;
        int h = i >> 12, ij = i & 4095, r = ij >> 6, c = ij & 63;
        float v = 0.0f;
        if (r < 49 && c < 49) {
            int rpi = (r / 7 - c / 7 + 6) * 13 + (r % 7 - c % 7 + 6);
            v = bias_table[rpi * 6 + h];
        }
        biasM[i] = v;
    }
}

// ---------------- fused main kernel: 1 window per 256-thread block, 2 blocks/CU ----------------
// LDS regions (manually carved, 78848 B total -> 2 blocks/CU):
//   q_s  [64][200] bf16  (later aliased as attention-output buffer ao)
//   k_s  [64][200] bf16
//   vt_s [192][72] bf16   vt[dim][token]
#define QS_STRIDE 200
#define VT_STRIDE 72

__global__ __launch_bounds__(256, 2) void wsa_main(
    const float* __restrict__ x, const float* __restrict__ bqkv,
    const __bf16* __restrict__ wqkvT, const __bf16* __restrict__ wprojT,
    const float* __restrict__ biasM, float* __restrict__ out)
{
    __shared__ __bf16 smem[64 * QS_STRIDE + 64 * QS_STRIDE + 192 * VT_STRIDE];
    __bf16* q_s = smem;                 // q, then ao (alias; safe: per-wave col h*32 read-before-write)
    __bf16* k_s = smem + 64 * QS_STRIDE;
    __bf16* vt_s = smem + 128 * QS_STRIDE;

    const int win = blockIdx.x;
    const int tid = (int)threadIdx.x;
    const int wave = tid >> 6;
    const int lane = tid & 63;
    const int g = lane >> 4;  // 0..3
    const int c = lane & 15;  // 0..15
    const float scale = 0.17677669529663687f;  // 32^-0.5

    // ---- Phase 1: qkv = x @ Wqkv + b  (M=64 padded, K=192, N=576) ----
    bf16x8 xa[4][6];
    {
        const long xbase = (long)win * 49 * 192;
#pragma unroll
        for (int mt = 0; mt < 4; ++mt) {
            int row = mt * 16 + c;
            bool ok = row < 49;
#pragma unroll
            for (int kk = 0; kk < 6; ++kk) {
                bf16x8 a;
                if (ok) {
                    const float* p = x + xbase + (long)row * 192 + kk * 32 + g * 8;
                    f32x4 v0 = *(const f32x4*)p;
                    f32x4 v1 = *(const f32x4*)(p + 4);
#pragma unroll
                    for (int j = 0; j < 4; ++j) { a[j] = (__bf16)v0[j]; a[4 + j] = (__bf16)v1[j]; }
                } else {
#pragma unroll
                    for (int j = 0; j < 8; ++j) a[j] = (__bf16)0.0f;
                }
                xa[mt][kk] = a;
            }
        }
    }

    for (int t = 0; t < 9; ++t) {
        int nt = wave * 9 + t;
        int col = nt * 16 + c;  // 0..575
        float bv = bqkv[col];
        f32x4 acc[4];
#pragma unroll
        for (int mt = 0; mt < 4; ++mt) { f32x4 z = {0.f, 0.f, 0.f, 0.f}; acc[mt] = z; }
#pragma unroll
        for (int kk = 0; kk < 6; ++kk) {
            bf16x8 b = *(const bf16x8*)(wqkvT + (long)col * 192 + kk * 32 + g * 8);
#pragma unroll
            for (int mt = 0; mt < 4; ++mt) acc[mt] = mfma16(xa[mt][kk], b, acc[mt]);
        }
#pragma unroll
        for (int mt = 0; mt < 4; ++mt) {
#pragma unroll
            for (int r = 0; r < 4; ++r) {
                int row = mt * 16 + g * 4 + r;
                float v = acc[mt][r] + bv;
                if (col < 192)       q_s[row * QS_STRIDE + col] = (__bf16)(v * scale);
                else if (col < 384)  k_s[row * QS_STRIDE + (col - 192)] = (__bf16)v;
                else                 vt_s[(col - 384) * VT_STRIDE + row] = (__bf16)v;
            }
        }
    }
    __syncthreads();

    // ---- Phase 2: attention, swapped QK^T (S^T = K·Q^T) so softmax is 4-lane-group ----
    // wave owns m-tile = wave (16 query rows: qrow_global = wave*16 + c)
    const int mt = wave;
    // mask addends for ktok = nt*16 + g*4 + r
    float nmask[4][4];
#pragma unroll
    for (int nt = 0; nt < 4; ++nt)
#pragma unroll
        for (int r = 0; r < 4; ++r)
            nmask[nt][r] = (nt * 16 + g * 4 + r < 49) ? 0.0f : -1e30f;
    const int srcA = ((g & 1) * 2) * 16 + c;  // src lane for jh=0
    const int srcB = srcA + 16;               // jh=1
    const int ghi = g >> 1;

    for (int h = 0; h < 6; ++h) {
        // B-fragment: Q[qrow=c][dim g*8+j]
        bf16x8 bq = *(const bf16x8*)&q_s[(mt * 16 + c) * QS_STRIDE + h * 32 + g * 8];
        f32x4 st[4];
#pragma unroll
        for (int nt = 0; nt < 4; ++nt) {
            // A-fragment: K[ktok = nt*16+c][dim g*8+j]
            bf16x8 ak = *(const bf16x8*)&k_s[(nt * 16 + c) * QS_STRIDE + h * 32 + g * 8];
            f32x4 z = {0.f, 0.f, 0.f, 0.f};
            st[nt] = mfma16(ak, bq, z);  // lane (g,c) reg r: S[qrow=c][ktok=nt*16+g*4+r]
        }
        // bias + mask; p[nt][r] in f32
        float p[4][4];
        const float* bh = biasM + h * 4096 + (mt * 16 + c) * 64;
#pragma unroll
        for (int nt = 0; nt < 4; ++nt) {
            f32x4 bb = *(const f32x4*)(bh + nt * 16 + g * 4);
#pragma unroll
            for (int r = 0; r < 4; ++r) p[nt][r] = st[nt][r] + bb[r] + nmask[nt][r];
        }
        // softmax over ktok: local 16 + 4-lane group (xor 16, 32)
        float m = p[0][0];
#pragma unroll
        for (int nt = 0; nt < 4; ++nt)
#pragma unroll
            for (int r = 0; r < 4; ++r) m = fmaxf(m, p[nt][r]);
        m = fmaxf(m, __shfl_xor(m, 16));
        m = fmaxf(m, __shfl_xor(m, 32));
        float sum = 0.f;
#pragma unroll
        for (int nt = 0; nt < 4; ++nt)
#pragma unroll
            for (int r = 0; r < 4; ++r) {
                float e = __expf(p[nt][r] - m);
                p[nt][r] = e;
                sum += e;
            }
        sum += __shfl_xor(sum, 16);
        sum += __shfl_xor(sum, 32);
        float pinv = 1.0f / sum;
        // pack to bf16 words: w[nt][rp] = {P[2rp] lo, P[2rp+1] hi}
        u32 w[4][2];
#pragma unroll
        for (int nt = 0; nt < 4; ++nt)
#pragma unroll
            for (int rp = 0; rp < 2; ++rp)
                w[nt][rp] = packbf(p[nt][2 * rp] * pinv, p[nt][2 * rp + 1] * pinv);
        // redistribute to PV A-fragment: pa[ks] halfword j = P[qrow=c][k=ks*32+g*8+j]
        // dest word jw=2*jh+rp <- w[2ks+(g>>1)][rp] from lane (2*(g&1)+jh)*16+c
        u32 paw[2][4];
#pragma unroll
        for (int ks = 0; ks < 2; ++ks)
#pragma unroll
            for (int jw = 0; jw < 4; ++jw) {
                int jh = jw >> 1, rp = jw & 1;
                int src = jh ? srcB : srcA;
                u32 R1 = (u32)__shfl((int)w[2 * ks][rp], src);
                u32 R2 = (u32)__shfl((int)w[2 * ks + 1][rp], src);
                paw[ks][jw] = ghi ? R2 : R1;
            }
        bf16x8 pa0, pa1;
        {
            u32x4 t0 = {paw[0][0], paw[0][1], paw[0][2], paw[0][3]};
            u32x4 t1 = {paw[1][0], paw[1][1], paw[1][2], paw[1][3]};
            pa0 = __builtin_bit_cast(bf16x8, t0);
            pa1 = __builtin_bit_cast(bf16x8, t1);
        }
        // PV: (16x64) @ (64x32)
        f32x4 o0, o1;
        { f32x4 z = {0.f, 0.f, 0.f, 0.f}; o0 = z; o1 = z; }
        {
            bf16x8 bv0 = *(const bf16x8*)&vt_s[(h * 32 + c) * VT_STRIDE + 0 * 32 + g * 8];
            bf16x8 bv1 = *(const bf16x8*)&vt_s[(h * 32 + 16 + c) * VT_STRIDE + 0 * 32 + g * 8];
            o0 = mfma16(pa0, bv0, o0);
            o1 = mfma16(pa0, bv1, o1);
        }
        {
            bf16x8 bv0 = *(const bf16x8*)&vt_s[(h * 32 + c) * VT_STRIDE + 1 * 32 + g * 8];
            bf16x8 bv1 = *(const bf16x8*)&vt_s[(h * 32 + 16 + c) * VT_STRIDE + 1 * 32 + g * 8];
            o0 = mfma16(pa1, bv0, o0);
            o1 = mfma16(pa1, bv1, o1);
        }
        // write attention-out into q_s alias (cols h*32.. already consumed this head, same wave/rows)
#pragma unroll
        for (int r = 0; r < 4; ++r) {
            int row = mt * 16 + g * 4 + r;
            q_s[row * QS_STRIDE + h * 32 + c] = (__bf16)o0[r];
            q_s[row * QS_STRIDE + h * 32 + 16 + c] = (__bf16)o1[r];
        }
    }
    __syncthreads();

    // ---- Phase 3: out = ao @ Wproj  (M=64, K=192, N=192); ao lives in q_s ----
    bf16x8 pa2[4][6];
#pragma unroll
    for (int m2 = 0; m2 < 4; ++m2)
#pragma unroll
        for (int kk = 0; kk < 6; ++kk)
            pa2[m2][kk] = *(const bf16x8*)&q_s[(m2 * 16 + c) * QS_STRIDE + kk * 32 + g * 8];

    for (int t = 0; t < 3; ++t) {
        int nt = wave * 3 + t;
        int col = nt * 16 + c;  // 0..191
        f32x4 acc[4];
#pragma unroll
        for (int m2 = 0; m2 < 4; ++m2) { f32x4 z = {0.f, 0.f, 0.f, 0.f}; acc[m2] = z; }
#pragma unroll
        for (int kk = 0; kk < 6; ++kk) {
            bf16x8 b = *(const bf16x8*)(wprojT + (long)col * 192 + kk * 32 + g * 8);
#pragma unroll
            for (int m2 = 0; m2 < 4; ++m2) acc[m2] = mfma16(pa2[m2][kk], b, acc[m2]);
        }
#pragma unroll
        for (int m2 = 0; m2 < 4; ++m2) {
#pragma unroll
            for (int r = 0; r < 4; ++r) {
                int row = m2 * 16 + g * 4 + r;
                if (row < 49)
                    out[((long)win * 49 + row) * 192 + col] = acc[m2][r];
            }
        }
    }
}

extern "C" void kernel_launch(void* const* d_in, const int* in_sizes, int n_in,
                              void* d_out, int out_size, void* d_ws, size_t ws_size,
                              hipStream_t stream)
{
    const float* x = (const float*)d_in[0];
    const float* w_qkv = (const float*)d_in[1];
    const float* b_qkv = (const float*)d_in[2];
    const float* bias_table = (const float*)d_in[3];
    const float* w_proj = (const float*)d_in[4];
    float* out = (float*)d_out;

    char* ws = (char*)d_ws;
    __bf16* wqkvT = (__bf16*)ws;
    __bf16* wprojT = (__bf16*)(ws + OFF_WPROJT);
    float* biasM = (float*)(ws + OFF_BIASM);

    wsa_prep<<<672, 256, 0, stream>>>(w_qkv, w_proj, bias_table, wqkvT, wprojT, biasM);
    wsa_main<<<4096, 256, 0, stream>>>(x, b_qkv, wqkvT, wprojT, biasM, out);
}